// Round 11
// baseline (168.392 us; speedup 1.0000x reference)
//
#include <hip/hip_runtime.h>

#define B_  4
#define NN_ 20
#define C_  128
#define H_  8
#define W_  32
#define P_  256      // H*W
#define GS_ 32
#define L_  1024     // GS*GS
#define K_  5120     // NN*P

// ---------------- ws layout (float elements) ----------------
// ind   : int   [B*L*NN]     @ 0        (81920)
// Kscal : float [B*L*NN]     @ 81920    (81920)
// eRc   : float [360*P]      @ 163840   (92160)   exp(rays-conv)
// ePc   : float [B*NN*P]     @ 256000   (20480)   exp(pano-conv)
// S     : float [B*360*NN]   @ 276480   (28800)   sum_p eRc*ePc
// Ft    : float [B*K*C]      @ 325632   (2621440)
// G     : float [B*360*NN*C] @ 2947072  (3686400)
// total 6633472 floats = 26.5 MB; capacity >= 28.56 MB proven (r6 NS=8 ran)

// ---- single fused front-end:
//   bid   0..359 : rays conv -> eRc = exp(conv)
//   bid 360..439 : pano stats (inline) + pano conv -> ePc = exp(conv)
//   bid 440..759 : geo -> ind, Kscal (ov terms dropped: softmax-shift-invariant)
//   bid 760..1079: feats transpose -> Ft
__global__ __launch_bounds__(256) void k_front(const float* __restrict__ feats,
                                               const float* __restrict__ rays,
                                               const float* __restrict__ bbox,
                                               const float* __restrict__ locs,
                                               const float* __restrict__ w1,
                                               const float* __restrict__ w2,
                                               const float* __restrict__ b1,
                                               const float* __restrict__ b2,
                                               const float* __restrict__ fw,
                                               const float* __restrict__ fb,
                                               float* __restrict__ eRc,
                                               float* __restrict__ ePc,
                                               int* __restrict__ ind,
                                               float* __restrict__ Kscal,
                                               float* __restrict__ Ft) {
  __shared__ float s[32 * 257];
  int bid = blockIdx.x, tid = threadIdx.x;
  if (bid < 360) {
    int a = bid;                                 // 360 angles
    #pragma unroll
    for (int c = 0; c < 3; ++c) s[c * P_ + tid] = rays[(a * 3 + c) * P_ + tid];
    __syncthreads();
    int y = tid >> 5, x = tid & 31;
    float acc1 = 0.f, acc2 = 0.f;
    #pragma unroll
    for (int c = 0; c < 3; ++c) {
      const float* sc  = s + c * P_;
      const float* w1c = w1 + (1 + c) * 9;
      const float* w2c = w2 + (1 + c) * 25;
      #pragma unroll
      for (int dy = 0; dy < 3; ++dy) { int yy = ((y + dy + 7) & 7) * 32;
        #pragma unroll
        for (int dx = 0; dx < 3; ++dx) { int xx = (x + dx + 31) & 31;
          acc1 += sc[yy + xx] * w1c[dy * 3 + dx]; } }
      #pragma unroll
      for (int dy = 0; dy < 5; ++dy) { int yy = ((y + dy + 6) & 7) * 32;
        #pragma unroll
        for (int dx = 0; dx < 5; ++dx) { int xx = (x + dx + 30) & 31;
          acc2 += sc[yy + xx] * w2c[dy * 5 + dx]; } }
    }
    eRc[a * P_ + tid] = expf(fw[0] * acc1 + fw[1] * acc2);
  } else if (bid < 440) {
    int bn = bid - 360;                          // b*NN + n
    const float* src = feats + bn * C_ * P_ + tid;
    float mx = -3.4e38f, sm = 0.f;
    #pragma unroll 8
    for (int c = 0; c < C_; ++c) { float v = src[c * P_]; mx = fmaxf(mx, v); sm += v; }
    s[tid]      = mx;
    s[P_ + tid] = sm * (1.0f / 128.0f);
    __syncthreads();
    int y = tid >> 5, x = tid & 31;
    float acc1 = 0.f, acc2 = 0.f;
    #pragma unroll
    for (int c = 0; c < 2; ++c) {
      const float* sc  = s + c * P_;
      const float* w1c = w1 + (4 + c) * 9;
      const float* w2c = w2 + (4 + c) * 25;
      #pragma unroll
      for (int dy = 0; dy < 3; ++dy) { int yy = ((y + dy + 7) & 7) * 32;
        #pragma unroll
        for (int dx = 0; dx < 3; ++dx) { int xx = (x + dx + 31) & 31;
          acc1 += sc[yy + xx] * w1c[dy * 3 + dx]; } }
      #pragma unroll
      for (int dy = 0; dy < 5; ++dy) { int yy = ((y + dy + 6) & 7) * 32;
        #pragma unroll
        for (int dx = 0; dx < 5; ++dx) { int xx = (x + dx + 30) & 31;
          acc2 += sc[yy + xx] * w2c[dy * 5 + dx]; } }
    }
    ePc[bn * P_ + tid] = expf(fw[0] * acc1 + fw[1] * acc2);
  } else if (bid < 760) {
    int t = (bid - 440) * 256 + tid;             // B*L*NN = 81920
    int n = t % NN_;
    int r = t / NN_;                             // b*L + l
    int l = r & 1023, b = r >> 10;
    int i = l >> 5, j = l & 31;
    float y0 = bbox[b * 4 + 0], x0 = bbox[b * 4 + 1];
    float y1 = bbox[b * 4 + 2], x1 = bbox[b * 4 + 3];
    float gy = (i == 31) ? y1 : (y0 + ((y1 - y0) / 31.0f) * (float)i);
    float gx = (j == 31) ? x1 : (x0 + ((x1 - x0) / 31.0f) * (float)j);
    float d0 = gy - locs[(b * NN_ + n) * 2 + 0];
    float d1 = gx - locs[(b * NN_ + n) * 2 + 1];
    float D  = sqrtf(d0 * d0 + d1 * d1 + 1e-12f);
    float th = atan2f(d1, d0);
    if (th < 0.f) th += 6.283185307179586f;
    float deg = th * 57.29577951308232f;
    int di = (int)rintf(deg);
    if (di >= 360) di -= 360;
    float s10 = 0.f, s20 = 0.f;
    #pragma unroll
    for (int q = 0; q < 9; ++q) s10 += w1[q];
    #pragma unroll
    for (int q = 0; q < 25; ++q) s20 += w2[q];
    ind[t]   = di;
    Kscal[t] = fw[0] * (D * s10 + b1[0]) + fw[1] * (D * s20 + b2[0]) + fb[0];
  } else {
    int bb = bid - 760;                          // 320 = (b*NN+n)*4 + c-quarter
    int bn = bb >> 2, cq = bb & 3;
    int b = bn / NN_, n = bn % NN_;
    int c0 = cq * 32;
    #pragma unroll 4
    for (int cc = 0; cc < 32; ++cc)
      s[cc * 257 + tid] = feats[(bn * C_ + c0 + cc) * P_ + tid];
    __syncthreads();
    int c = tid & 31, p8 = tid >> 5;
    #pragma unroll 4
    for (int pp = 0; pp < 32; ++pp) {
      int p = pp * 8 + p8;
      Ft[((size_t)b * K_ + n * P_ + p) * C_ + c0 + c] = s[c * 257 + p];
    }
  }
}

// G[b,a,n,c] = sum_p eRc[a,p]*ePc[b,n,p]*Ft[b,(n,p),c]
// S[b,a,n]   = sum_p eRc[a,p]*ePc[b,n,p]   (softmax denominator table)
// r8-proven structure: 32a x 128c tile, 2 chunks of 128 p, 4 waves, q-split,
// 2-stage Ft pipeline. sW staging folds in the ePc factor; S is a column-sum
// of sW by wave-0 lanes 0-31 (conflict-free, hidden under other waves' FMAs).
__global__ __launch_bounds__(256) void k_G(const float* __restrict__ eRc,
                                           const float* __restrict__ ePc,
                                           const float* __restrict__ Ft,
                                           float* __restrict__ G,
                                           float* __restrict__ S) {
  __shared__ __align__(16) float sW[128 * 36];   // sW[p][a], stride 36: b128 align
  int bid = blockIdx.x;
  int at = bid % 12;
  int n  = (bid / 12) % NN_;
  int b  = bid / 240;
  int a0 = at << 5;                              // 32 a per block
  int tid = threadIdx.x;
  int w8 = (tid >> 6) << 3;                      // wave * 8 -> a offset
  int lane = tid & 63;
  int q  = lane >> 4;                            // 0..3 : p offset within 4-p step
  int c0 = (lane & 15) << 2;                     // c 0..60 (lo half), +64 (hi half)
  int kst = tid & 127, hst = tid >> 7;           // staging role: p, a-half
  float4 aL[8], aH[8];
  #pragma unroll
  for (int r = 0; r < 8; ++r) {
    aL[r] = make_float4(0.f, 0.f, 0.f, 0.f);
    aH[r] = make_float4(0.f, 0.f, 0.f, 0.f);
  }
  float sS = 0.f;
  const float* epc   = ePc + (b * NN_ + n) * P_;
  const float* fbase = Ft + ((size_t)(b * NN_ + n) * P_ + q) * C_ + c0;
  for (int pc0 = 0; pc0 < 256; pc0 += 128) {
    __syncthreads();                             // all waves done reading sW
    #pragma unroll
    for (int r = 0; r < 16; ++r) {               // 128 p x 32 a, 16 elems/thread
      int ar = a0 + hst * 16 + r;
      if (ar > 359) ar = 359;                    // clamp: in-bounds, unused rows
      sW[kst * 36 + hst * 16 + r] = eRc[ar * P_ + pc0 + kst] * epc[pc0 + kst];
    }
    __syncthreads();
    if (tid < 32) {                              // S partial: column a=tid of sW
      float t = 0.f;
      #pragma unroll 8
      for (int p = 0; p < 128; ++p) t += sW[p * 36 + tid];
      sS += t;
    }
    const float* fp  = fbase + (size_t)pc0 * C_;
    const float* swk = sW + q * 36 + w8;
#define FMA8(r, wgt, f0, f1) \
    aL[r].x += (wgt) * f0.x; aL[r].y += (wgt) * f0.y; \
    aL[r].z += (wgt) * f0.z; aL[r].w += (wgt) * f0.w; \
    aH[r].x += (wgt) * f1.x; aH[r].y += (wgt) * f1.y; \
    aH[r].z += (wgt) * f1.z; aH[r].w += (wgt) * f1.w;
#define FMA64(wa, wb, f0, f1) \
    FMA8(0, wa.x, f0, f1) FMA8(1, wa.y, f0, f1) FMA8(2, wa.z, f0, f1) \
    FMA8(3, wa.w, f0, f1) FMA8(4, wb.x, f0, f1) FMA8(5, wb.y, f0, f1) \
    FMA8(6, wb.z, f0, f1) FMA8(7, wb.w, f0, f1)
    float4 fa0 = *(const float4*)(fp);
    float4 fb0 = *(const float4*)(fp + 64);
    #pragma unroll
    for (int kk = 0; kk < 128; kk += 8) {
      float4 fa1 = *(const float4*)(fp + (size_t)(kk + 4) * C_);
      float4 fb1 = *(const float4*)(fp + (size_t)(kk + 4) * C_ + 64);
      float4 wa  = *(const float4*)(swk + kk * 36);
      float4 wb  = *(const float4*)(swk + kk * 36 + 4);
      FMA64(wa, wb, fa0, fb0)
      int pk = (kk + 8 < 128) ? (kk + 8) : 0;    // folds at compile time
      fa0 = *(const float4*)(fp + (size_t)pk * C_);
      fb0 = *(const float4*)(fp + (size_t)pk * C_ + 64);
      wa  = *(const float4*)(swk + (kk + 4) * 36);
      wb  = *(const float4*)(swk + (kk + 4) * 36 + 4);
      FMA64(wa, wb, fa1, fb1)
    }
#undef FMA64
#undef FMA8
  }
  // combine the 4 q-partials (lane bits 4,5)
#define RED2(v) { v += __shfl_xor(v, 16); v += __shfl_xor(v, 32); }
  #pragma unroll
  for (int r = 0; r < 8; ++r) {
    RED2(aL[r].x) RED2(aL[r].y) RED2(aL[r].z) RED2(aL[r].w)
    RED2(aH[r].x) RED2(aH[r].y) RED2(aH[r].z) RED2(aH[r].w)
  }
#undef RED2
  // q-group g writes a-rows {2g, 2g+1}
  #pragma unroll
  for (int r = 0; r < 8; ++r) {
    if ((r >> 1) == q) {
      int a = a0 + w8 + r;
      if (a < 360) {
        float* pt = G + (((size_t)b * 360 + a) * NN_ + n) * C_;
        *(float4*)(pt + c0)      = aL[r];
        *(float4*)(pt + c0 + 64) = aH[r];
      }
    }
  }
  if (tid < 32) {
    int a = a0 + tid;
    if (a < 360) S[((size_t)b * 360 + a) * NN_ + n] = sS;
  }
}

// FACTORED attn + gf, 4 grid cells per block (1024 blocks), float4 I/O:
//   Z = sum_n e^{Ks}*S[i,n];  attn[n,p] = (e^{Ks_n}/Z)*eRc[i_n,p]*ePc[n,p];
//   gf[c] = sum_n (e^{Ks_n}/Z)*G[i_n,n,c].
// attn mapping: wave w (tid>>6) covers n in {w, w+4, ..., w+16}; lane&63 ->
// 4 consecutive pixels -> float4 loads/stores, 4x fewer VMEM instructions.
// Elementwise arithmetic (wn*er)*ep and gf's sequential n-order match r10
// exactly -> bitwise-identical outputs.
__global__ __launch_bounds__(256) void k_soft(const float* __restrict__ eRc,
                                              const float* __restrict__ ePc,
                                              const float* __restrict__ Kscal,
                                              const int* __restrict__ ind,
                                              const float* __restrict__ S,
                                              const float* __restrict__ G,
                                              float* __restrict__ attn,
                                              float* __restrict__ gf) {
  int bl0 = blockIdx.x << 2;                     // 4 cells share b (aligned)
  int b = bl0 >> 10;
  int tid = threadIdx.x;
  __shared__ float sE[4][NN_];                   // e^{Ks}
  __shared__ int   sI[4][NN_];
  __shared__ float sZ[4][NN_];                   // e^{Ks} * S[i,n]
  if (tid < 4 * NN_) {
    int cell = tid / NN_, n = tid % NN_;
    int bl = bl0 + cell;
    int i = ind[bl * NN_ + n];
    float ek = expf(Kscal[bl * NN_ + n]);
    sI[cell][n] = i;
    sE[cell][n] = ek;
    sZ[cell][n] = ek * S[((size_t)b * 360 + i) * NN_ + n];
  }
  __syncthreads();
  int w  = tid >> 6;                             // wave -> n offset
  int c4 = (tid & 63) << 2;                      // 4 consecutive pixels
  #pragma unroll
  for (int cell = 0; cell < 4; ++cell) {
    int bl = bl0 + cell;
    float Z = 0.f;
    #pragma unroll
    for (int n = 0; n < NN_; ++n) Z += sZ[cell][n];
    float invZ = 1.0f / Z;
    #pragma unroll
    for (int j = 0; j < 5; ++j) {
      int n = w + 4 * j;
      float wn = sE[cell][n] * invZ;
      float4 er = *(const float4*)&eRc[sI[cell][n] * P_ + c4];
      float4 ep = *(const float4*)&ePc[(b * NN_ + n) * P_ + c4];
      float4 o;
      o.x = (wn * er.x) * ep.x;
      o.y = (wn * er.y) * ep.y;
      o.z = (wn * er.z) * ep.z;
      o.w = (wn * er.w) * ep.w;
      *(float4*)&attn[((size_t)bl * NN_ + n) * P_ + c4] = o;
    }
  }
  if (tid < C_) {                                // gf gather, sequential n order
    #pragma unroll
    for (int cell = 0; cell < 4; ++cell) {
      int bl = bl0 + cell;
      float Z = 0.f;
      #pragma unroll
      for (int n = 0; n < NN_; ++n) Z += sZ[cell][n];
      float invZ = 1.0f / Z;
      float acc = 0.f;
      #pragma unroll
      for (int n = 0; n < NN_; ++n)
        acc += (sE[cell][n] * invZ)
             * G[(((size_t)b * 360 + sI[cell][n]) * NN_ + n) * C_ + tid];
      gf[(size_t)bl * C_ + tid] = acc;
    }
  }
}

extern "C" void kernel_launch(void* const* d_in, const int* in_sizes, int n_in,
                              void* d_out, int out_size, void* d_ws, size_t ws_size,
                              hipStream_t stream) {
  const float* bbox  = (const float*)d_in[0];
  const float* locs  = (const float*)d_in[1];
  const float* feats = (const float*)d_in[2];
  const float* rays  = (const float*)d_in[4];
  const float* w1    = (const float*)d_in[5];
  const float* b1    = (const float*)d_in[6];
  const float* w2    = (const float*)d_in[7];
  const float* b2    = (const float*)d_in[8];
  const float* fw    = (const float*)d_in[9];
  const float* fb    = (const float*)d_in[10];

  float* ws     = (float*)d_ws;
  int*   ind    = (int*)ws;
  float* Kscal  = ws + 81920;
  float* eRc    = ws + 163840;
  float* ePc    = ws + 256000;
  float* S      = ws + 276480;
  float* Ft     = ws + 325632;
  float* G      = ws + 2947072;

  float* gf   = (float*)d_out;
  float* attn = gf + (B_ * L_ * C_);             // 20.97M floats

  k_front<<<1080, 256, 0, stream>>>(feats, rays, bbox, locs, w1, w2, b1, b2,
                                    fw, fb, eRc, ePc, ind, Kscal, Ft);
  k_G    <<<960, 256, 0, stream>>>(eRc, ePc, Ft, G, S);
  k_soft <<<1024, 256, 0, stream>>>(eRc, ePc, Kscal, ind, S, G, attn, gf);
}